// Round 2
// baseline (2107.700 us; speedup 1.0000x reference)
//
#include <hip/hip_runtime.h>
#include <hip/hip_bf16.h>

#define NN 256
#define CCH 512
#define TT 4
#define SS 64
#define LL 256

typedef unsigned short u16;
typedef unsigned int u32;

typedef __bf16 bf16_t;
typedef bf16_t bf16x8 __attribute__((ext_vector_type(8)));
typedef float f32x16 __attribute__((ext_vector_type(16)));

__device__ __forceinline__ float bf2f(u32 h){
    return __uint_as_float(h << 16);
}
__device__ __forceinline__ u16 f2bf(float f){
    u32 u = __float_as_uint(f);
    u32 r = u + 0x7fffu + ((u >> 16) & 1u);
    return (u16)(r >> 16);
}
__device__ __forceinline__ bf16x8 ldg8(const u16* p){
    uint4 q = *(const uint4*)p;          // 16B aligned by construction
    return __builtin_bit_cast(bf16x8, q);
}

// ---------------------------------------------------------------------------
// Weight transpose: W[o][c][tap] fp32  ->  Wt[((tap*32 + c/16)*512 + o)*16 + c%16] bf16
// ---------------------------------------------------------------------------
__global__ __launch_bounds__(256) void wt_kernel(
    const float* __restrict__ W, u16* __restrict__ Wt)
{
    const int e = blockIdx.x * 256 + threadIdx.x;     // 0 .. 9*32*512*16-1
    const int cl  = e & 15;
    const int o   = (e >> 4) & 511;
    const int cg  = (e >> 13) & 31;
    const int tap = e >> 18;
    Wt[e] = f2bf(W[((size_t)o * CCH + cg * 16 + cl) * 9 + tap]);
}

// ---------------------------------------------------------------------------
// Implicit-GEMM conv via MFMA 32x32x16 bf16 — barrier-free per-wave pipeline.
// Block: n = blockIdx.x, o-base = blockIdx.y*128. Wave w = t-plane w.
// Each wave owns its plane: stages its own 100x40 LDS tile (double-buffered),
// computes 128 o x 64 locs (acc[4][2]). No __syncthreads anywhere.
// LDS c-stride 40 u16 (80 B): B-frags are single aligned ds_read_b128,
// bank-start (20cc+8r+4h)%32 -> 8 lanes/bank = conflict-free optimum.
// ---------------------------------------------------------------------------
__global__ __launch_bounds__(256, 2) void conv_mfma_kernel(
    const float* __restrict__ x, const u16* __restrict__ Wt, u16* __restrict__ outb)
{
    __shared__ u16 lds[8 * 4000];        // [wave][buf][sp 100][c 40] = 64 KB
    const int tid = threadIdx.x;
    const int n  = blockIdx.x;
    const int ob = blockIdx.y * 128;
    const int lane = tid & 63;
    const int w  = tid >> 6;             // wave = t-plane
    const int h   = lane >> 5;
    const int col = lane & 31;
    const int r  = col >> 3, cc = col & 7;

    // zero this wave's two buffers once; borders stay 0 = conv padding
    {
        u32* wb = (u32*)(lds + w * 8000);
        for (int i = lane; i < 4000; i += 64) wb[i] = 0;
    }

    f32x16 acc[4][2];
    #pragma unroll
    for (int m = 0; m < 4; ++m)
      #pragma unroll
      for (int nt = 0; nt < 2; ++nt)
        #pragma unroll
        for (int e = 0; e < 16; ++e) acc[m][nt][e] = 0.f;

    const int g  = lane >> 4;            // c-granule 0..3 (8 c each)
    const int s4 = (lane & 15) << 2;     // spatial base 0,4,..,60

    int bbase[2];
    #pragma unroll
    for (int nt = 0; nt < 2; ++nt)
        bbase[nt] = ((nt * 4 + r) * 10 + cc) * 40 + h * 8;

    const size_t abase = (size_t)(ob + col) * 16 + h * 8;

    // ---- staging helpers (per-wave, own plane only) ----
    auto stage_load = [&](int ch, float4* xv){
        const float* xr = x + (((size_t)n * CCH + ch * 32 + g * 8) * TT + w) * SS + s4;
        #pragma unroll
        for (int c2 = 0; c2 < 8; ++c2)
            xv[c2] = *(const float4*)(xr + (size_t)c2 * (TT * SS));
    };
    auto stage_write = [&](int ch, const float4* xv){
        u16* wb = lds + w * 8000 + (ch & 1) * 4000;
        #pragma unroll
        for (int i = 0; i < 4; ++i){
            const int s = s4 + i;
            const int sp = ((s >> 3) + 1) * 10 + (s & 7) + 1;
            uint4 pw;
            pw.x = (u32)f2bf(((const float*)&xv[0])[i]) | ((u32)f2bf(((const float*)&xv[1])[i]) << 16);
            pw.y = (u32)f2bf(((const float*)&xv[2])[i]) | ((u32)f2bf(((const float*)&xv[3])[i]) << 16);
            pw.z = (u32)f2bf(((const float*)&xv[4])[i]) | ((u32)f2bf(((const float*)&xv[5])[i]) << 16);
            pw.w = (u32)f2bf(((const float*)&xv[6])[i]) | ((u32)f2bf(((const float*)&xv[7])[i]) << 16);
            *(uint4*)&wb[sp * 40 + g * 8] = pw;
        }
    };

    // prologue: stage ch 0 into buf 0
    {
        float4 xv[8];
        stage_load(0, xv);
        stage_write(0, xv);
    }

    for (int ch = 0; ch < 16; ++ch){
        float4 xv[8];
        if (ch < 15) stage_load(ch + 1, xv);        // in flight under compute

        const u16* wb = lds + w * 8000 + (ch & 1) * 4000;
        #pragma unroll
        for (int tap = 0; tap < 9; ++tap){
            const int tof = ((tap / 3) * 10 + (tap % 3)) * 40;
            #pragma unroll
            for (int ks = 0; ks < 2; ++ks){
                const size_t ai = (size_t)(tap * 32 + ch * 2 + ks) * 8192 + abase;
                bf16x8 a[4];
                #pragma unroll
                for (int m = 0; m < 4; ++m) a[m] = ldg8(Wt + ai + 512 * m);
                bf16x8 b[2];
                #pragma unroll
                for (int nt = 0; nt < 2; ++nt)
                    b[nt] = ldg8(&wb[bbase[nt] + tof + ks * 16]);
                #pragma unroll
                for (int m = 0; m < 4; ++m)
                  #pragma unroll
                  for (int nt = 0; nt < 2; ++nt)
                    acc[m][nt] = __builtin_amdgcn_mfma_f32_32x32x16_bf16(a[m], b[nt], acc[m][nt], 0, 0, 0);
            }
        }
        if (ch < 15) stage_write(ch + 1, xv);
    }

    // epilogue: bf16 store to [loc][n][c]
    #pragma unroll
    for (int m = 0; m < 4; ++m){
        #pragma unroll
        for (int nt = 0; nt < 2; ++nt){
            const int loc = w * 64 + nt * 32 + col;
            u16* orow = outb + ((size_t)loc * NN + n) * CCH + ob + m * 32;
            #pragma unroll
            for (int g2 = 0; g2 < 4; ++g2){
                uint2 val;
                val.x = (u32)f2bf(acc[m][nt][g2 * 4 + 0]) | ((u32)f2bf(acc[m][nt][g2 * 4 + 1]) << 16);
                val.y = (u32)f2bf(acc[m][nt][g2 * 4 + 2]) | ((u32)f2bf(acc[m][nt][g2 * 4 + 3]) << 16);
                *(uint2*)&orow[g2 * 8 + h * 4] = val;
            }
        }
    }
}

// ---------------------------------------------------------------------------
// conv_out: same barrier-free structure; staging applies GroupNorm+affine+ReLU
// while converting virt; epilogue adds residual x, stores fp32 [n][c][t][s].
// ---------------------------------------------------------------------------
__global__ __launch_bounds__(256, 2) void conv_out_mfma_kernel(
    const u16* __restrict__ virtb, const u16* __restrict__ Wt,
    const float* __restrict__ x, const float* __restrict__ gamma,
    const float* __restrict__ beta, const float* __restrict__ musig,
    float* __restrict__ out)
{
    __shared__ u16 lds[8 * 4000];
    const int tid = threadIdx.x;
    const int n  = blockIdx.x;
    const int ob = blockIdx.y * 128;
    const int lane = tid & 63;
    const int w  = tid >> 6;
    const int h   = lane >> 5;
    const int col = lane & 31;
    const int r  = col >> 3, cc = col & 7;

    const float mu   = musig[2 * n];
    const float rsig = musig[2 * n + 1];

    {
        u32* wb = (u32*)(lds + w * 8000);
        for (int i = lane; i < 4000; i += 64) wb[i] = 0;
    }

    f32x16 acc[4][2];
    #pragma unroll
    for (int m = 0; m < 4; ++m)
      #pragma unroll
      for (int nt = 0; nt < 2; ++nt)
        #pragma unroll
        for (int e = 0; e < 16; ++e) acc[m][nt][e] = 0.f;

    const int g  = lane >> 4;
    const int s4 = (lane & 15) << 2;

    int bbase[2];
    #pragma unroll
    for (int nt = 0; nt < 2; ++nt)
        bbase[nt] = ((nt * 4 + r) * 10 + cc) * 40 + h * 8;

    const size_t abase = (size_t)(ob + col) * 16 + h * 8;

    auto stage_load = [&](int ch, uint4* vv){
        #pragma unroll
        for (int i = 0; i < 4; ++i)
            vv[i] = *(const uint4*)(virtb + ((size_t)(w * 64 + s4 + i) * NN + n) * CCH + ch * 32 + g * 8);
    };
    auto stage_write = [&](int ch, const uint4* vv){
        const float* gp = gamma + ch * 32 + g * 8;
        const float* bp = beta  + ch * 32 + g * 8;
        const float4 ga0 = *(const float4*)gp;
        const float4 ga1 = *(const float4*)(gp + 4);
        const float4 be0 = *(const float4*)bp;
        const float4 be1 = *(const float4*)(bp + 4);
        float gsc[8], off[8];
        const float gav[8] = {ga0.x, ga0.y, ga0.z, ga0.w, ga1.x, ga1.y, ga1.z, ga1.w};
        const float bev[8] = {be0.x, be0.y, be0.z, be0.w, be1.x, be1.y, be1.z, be1.w};
        #pragma unroll
        for (int c2 = 0; c2 < 8; ++c2){
            gsc[c2] = gav[c2] * rsig;
            off[c2] = bev[c2] - mu * rsig * gav[c2];
        }
        u16* wb = lds + w * 8000 + (ch & 1) * 4000;
        #pragma unroll
        for (int i = 0; i < 4; ++i){
            const int s = s4 + i;
            const int sp = ((s >> 3) + 1) * 10 + (s & 7) + 1;
            const u32 q[4] = {vv[i].x, vv[i].y, vv[i].z, vv[i].w};
            u16 ov[8];
            #pragma unroll
            for (int c2 = 0; c2 < 8; ++c2){
                const u32 half = (c2 & 1) ? (q[c2 >> 1] >> 16) : (q[c2 >> 1] & 0xffffu);
                const float f = fmaxf(bf2f(half) * gsc[c2] + off[c2], 0.f);
                ov[c2] = f2bf(f);
            }
            uint4 pw;
            pw.x = (u32)ov[0] | ((u32)ov[1] << 16);
            pw.y = (u32)ov[2] | ((u32)ov[3] << 16);
            pw.z = (u32)ov[4] | ((u32)ov[5] << 16);
            pw.w = (u32)ov[6] | ((u32)ov[7] << 16);
            *(uint4*)&wb[sp * 40 + g * 8] = pw;
        }
    };

    {
        uint4 vv[4];
        stage_load(0, vv);
        stage_write(0, vv);
    }

    for (int ch = 0; ch < 16; ++ch){
        uint4 vv[4];
        if (ch < 15) stage_load(ch + 1, vv);

        const u16* wb = lds + w * 8000 + (ch & 1) * 4000;
        #pragma unroll
        for (int tap = 0; tap < 9; ++tap){
            const int tof = ((tap / 3) * 10 + (tap % 3)) * 40;
            #pragma unroll
            for (int ks = 0; ks < 2; ++ks){
                const size_t ai = (size_t)(tap * 32 + ch * 2 + ks) * 8192 + abase;
                bf16x8 a[4];
                #pragma unroll
                for (int m = 0; m < 4; ++m) a[m] = ldg8(Wt + ai + 512 * m);
                bf16x8 b[2];
                #pragma unroll
                for (int nt = 0; nt < 2; ++nt)
                    b[nt] = ldg8(&wb[bbase[nt] + tof + ks * 16]);
                #pragma unroll
                for (int m = 0; m < 4; ++m)
                  #pragma unroll
                  for (int nt = 0; nt < 2; ++nt)
                    acc[m][nt] = __builtin_amdgcn_mfma_f32_32x32x16_bf16(a[m], b[nt], acc[m][nt], 0, 0, 0);
            }
        }
        if (ch < 15) stage_write(ch + 1, vv);
    }

    // epilogue: out = x + conv, fp32 [n][c][t][s], p = w
    #pragma unroll
    for (int m = 0; m < 4; ++m){
        #pragma unroll
        for (int nt = 0; nt < 2; ++nt){
            const int s = nt * 32 + col;
            #pragma unroll
            for (int g2 = 0; g2 < 4; ++g2){
                const int o0 = ob + m * 32 + 8 * g2 + 4 * h;
                #pragma unroll
                for (int rr = 0; rr < 4; ++rr){
                    const size_t oi = (((size_t)n * CCH + o0 + rr) * TT + w) * SS + s;
                    out[oi] = x[oi] + acc[m][nt][g2 * 4 + rr];
                }
            }
        }
    }
}

// ---------------------------------------------------------------------------
// V transpose: vb [loc][n][c] -> vt [loc][c][n]  (unchanged)
// ---------------------------------------------------------------------------
__global__ __launch_bounds__(256) void vt_kernel(
    const u16* __restrict__ vb, u16* __restrict__ vt)
{
    __shared__ u16 ts[64][72];
    const int loc = blockIdx.x;
    const int n0 = (blockIdx.y & 3) * 64;
    const int c0 = (blockIdx.y >> 2) * 64;
    const int tid = threadIdx.x;
    const int rr = tid >> 3;          // 0..31
    const int ct = tid & 7;           // col-block / n-block
    #pragma unroll
    for (int q = 0; q < 2; ++q){
        const int row = rr + q * 32;
        const int key = (row & 7) ^ ((row >> 3) & 7);
        const uint4 v = *(const uint4*)(vb + ((size_t)loc * NN + n0 + row) * CCH + c0 + ct * 8);
        *(uint4*)&ts[row][(ct ^ key) << 3] = v;
    }
    __syncthreads();
    #pragma unroll
    for (int q = 0; q < 2; ++q){
        const int c = rr + q * 32;    // local c row of vt
        u16 tmp[8];
        #pragma unroll
        for (int e = 0; e < 8; ++e){
            const int n = ct * 8 + e;
            const int key = (n & 7) ^ ((n >> 3) & 7);   // = e ^ ct
            tmp[e] = ts[n][(((c >> 3) ^ key) << 3) + (c & 7)];
        }
        uint4 o;
        o.x = (u32)tmp[0] | ((u32)tmp[1] << 16);
        o.y = (u32)tmp[2] | ((u32)tmp[3] << 16);
        o.z = (u32)tmp[4] | ((u32)tmp[5] << 16);
        o.w = (u32)tmp[6] | ((u32)tmp[7] << 16);
        *(uint4*)(vt + ((size_t)loc * CCH + c0 + c) * NN + n0 + ct * 8) = o;
    }
}

// ---------------------------------------------------------------------------
// MFMA attention (unchanged from round 1).
// ---------------------------------------------------------------------------
__global__ __launch_bounds__(256, 3) void attn_mfma_kernel(
    const u16* __restrict__ qb, const u16* __restrict__ kb,
    const u16* __restrict__ vt, const int* __restrict__ roi,
    u16* __restrict__ virtb)
{
    __shared__ float Srow[32][264];      // 33.8 KB
    __shared__ u16 Pfrag[16 * 64 * 8];   // 16 KB, A-frag layout for PV
    __shared__ int roi_s[256];

    const int bid = blockIdx.x;
    const int loc = ((bid >> 6) << 3) | (bid & 7);   // XCD-coherent decode
    const int it  = (bid >> 3) & 7;
    const int i0  = it * 32;
    const int tid = threadIdx.x;
    const int lane = tid & 63;
    const int w   = tid >> 6;
    const int h   = lane >> 5;
    const int col = lane & 31;

    roi_s[tid] = roi[tid];

    // ---- Phase 1: QK^T, wave w owns j = w*64 .. w*64+63 ----
    f32x16 acc0, acc1;
    #pragma unroll
    for (int e = 0; e < 16; ++e){ acc0[e] = 0.f; acc1[e] = 0.f; }

    const u16* qp = qb + ((size_t)loc * NN + i0 + col) * CCH + h * 8;
    const u16* kp = kb + ((size_t)loc * NN + w * 64 + col) * CCH + h * 8;

    #pragma unroll 4
    for (int kc = 0; kc < 32; ++kc){
        const bf16x8 a  = ldg8(qp + kc * 16);
        const bf16x8 b0 = ldg8(kp + kc * 16);
        const bf16x8 b1 = ldg8(kp + 32 * CCH + kc * 16);
        acc0 = __builtin_amdgcn_mfma_f32_32x32x16_bf16(a, b0, acc0, 0, 0, 0);
        acc1 = __builtin_amdgcn_mfma_f32_32x32x16_bf16(a, b1, acc1, 0, 0, 0);
    }

    #pragma unroll
    for (int e = 0; e < 16; ++e){
        const int r = (e & 3) + 8 * (e >> 2) + 4 * h;
        Srow[r][w * 64 + col]      = acc0[e];
        Srow[r][w * 64 + 32 + col] = acc1[e];
    }
    __syncthreads();

    // ---- Phase 2: masked softmax, 8 threads per row ----
    {
        const int row = tid >> 3, u = tid & 7;
        const int myroi = roi_s[i0 + row];
        const float scale = 0.04419417382415922f;
        float ev[32];
        float mx = -1e30f;
        #pragma unroll
        for (int g = 0; g < 8; ++g){
            const float4 s4 = *(const float4*)&Srow[row][u * 4 + g * 32];
            const float ss[4] = {s4.x, s4.y, s4.z, s4.w};
            #pragma unroll
            for (int q = 0; q < 4; ++q){
                const int j = u * 4 + g * 32 + q;
                const float xv = (roi_s[j] == myroi) ? ss[q] * scale : -1e30f;
                ev[g * 4 + q] = xv;
                mx = fmaxf(mx, xv);
            }
        }
        mx = fmaxf(mx, __shfl_xor(mx, 1));
        mx = fmaxf(mx, __shfl_xor(mx, 2));
        mx = fmaxf(mx, __shfl_xor(mx, 4));
        float ssum = 0.f;
        #pragma unroll
        for (int q2 = 0; q2 < 32; ++q2){
            const float e2 = (ev[q2] > -1e29f) ? __expf(ev[q2] - mx) : 0.f;
            ev[q2] = e2;
            ssum += e2;
        }
        ssum += __shfl_xor(ssum, 1);
        ssum += __shfl_xor(ssum, 2);
        ssum += __shfl_xor(ssum, 4);
        const float rinv = 1.f / ssum;
        #pragma unroll
        for (int g = 0; g < 8; ++g){
            const int t    = 2 * g + (u >> 2);
            const int half = (u >> 1) & 1;
            const int e0   = (u & 1) * 4;
            uint2 pw;
            pw.x = (u32)f2bf(ev[g * 4 + 0] * rinv) | ((u32)f2bf(ev[g * 4 + 1] * rinv) << 16);
            pw.y = (u32)f2bf(ev[g * 4 + 2] * rinv) | ((u32)f2bf(ev[g * 4 + 3] * rinv) << 16);
            *(uint2*)&Pfrag[((t * 64 + half * 32 + row) << 3) + e0] = pw;
        }
    }
    __syncthreads();

    // ---- Phase 3: PV, wave w owns c = w*128 .. w*128+127 ----
    f32x16 pacc[4];
    #pragma unroll
    for (int jn = 0; jn < 4; ++jn)
        #pragma unroll
        for (int e = 0; e < 16; ++e) pacc[jn][e] = 0.f;

    const u16* vp = vt + ((size_t)loc * CCH + w * 128 + col) * NN + h * 8;
    #pragma unroll 2
    for (int t = 0; t < 16; ++t){
        const bf16x8 pa = ldg8(&Pfrag[(t * 64 + lane) << 3]);
        #pragma unroll
        for (int jn = 0; jn < 4; ++jn){
            const bf16x8 bv = ldg8(vp + (size_t)(jn * 32) * NN + t * 16);
            pacc[jn] = __builtin_amdgcn_mfma_f32_32x32x16_bf16(pa, bv, pacc[jn], 0, 0, 0);
        }
    }

    u16* op = virtb + ((size_t)loc * NN + i0) * CCH + w * 128 + col;
    #pragma unroll
    for (int jn = 0; jn < 4; ++jn){
        #pragma unroll
        for (int e = 0; e < 16; ++e){
            const int r = (e & 3) + 8 * (e >> 2) + 4 * h;
            op[(size_t)r * CCH + jn * 32] = f2bf(pacc[jn][e]);
        }
    }
}

// ---------------------------------------------------------------------------
// GroupNorm stats per sample.
// ---------------------------------------------------------------------------
__global__ __launch_bounds__(256) void stats_kernel(
    const u16* __restrict__ virtb, float* __restrict__ musig)
{
    const int n = blockIdx.x;
    const int tid = threadIdx.x;
    float s = 0.f, q = 0.f;
    for (int loc = 0; loc < LL; ++loc){
        const u32 v = *(const u32*)(virtb + ((size_t)loc * NN + n) * CCH + 2 * tid);
        const float a = bf2f(v & 0xffffu);
        const float b = bf2f(v >> 16);
        s += a + b;
        q += a * a + b * b;
    }
    #pragma unroll
    for (int off = 1; off < 64; off <<= 1){
        s += __shfl_xor(s, off);
        q += __shfl_xor(q, off);
    }
    __shared__ float red[8];
    const int wave = tid >> 6;
    if ((tid & 63) == 0){ red[wave * 2] = s; red[wave * 2 + 1] = q; }
    __syncthreads();
    if (tid == 0){
        const float S = red[0] + red[2] + red[4] + red[6];
        const float Q = red[1] + red[3] + red[5] + red[7];
        const float inv = 1.f / 131072.f;
        const float mval = S * inv;
        const float var = Q * inv - mval * mval;
        musig[2 * n]     = mval;
        musig[2 * n + 1] = rsqrtf(var + 1e-5f);
    }
}

__global__ void sentinel_kernel(float* out){
    const size_t i = (size_t)blockIdx.x * 256 + threadIdx.x;
    out[i] = 1.0e9f;
}

extern "C" void kernel_launch(void* const* d_in, const int* in_sizes, int n_in,
                              void* d_out, int out_size, void* d_ws, size_t ws_size,
                              hipStream_t stream)
{
    (void)in_sizes; (void)n_in; (void)out_size;
    const float* x   = (const float*)d_in[0];
    const int*   roi = (const int*)d_in[1];
    const float* Wq  = (const float*)d_in[2];
    const float* Wk  = (const float*)d_in[3];
    const float* Wv  = (const float*)d_in[4];
    const float* Wc  = (const float*)d_in[5];
    const float* gam = (const float*)d_in[6];
    const float* bet = (const float*)d_in[7];
    float* out = (float*)d_out;

    const size_t EL = 33554432ull;                 // N*C*T*H*W
    const size_t need = EL * 2ull * 4ull + 2048ull;
    if (ws_size < need){
        sentinel_kernel<<<131072, 256, 0, stream>>>(out);
        return;
    }
    u16* qb    = (u16*)d_ws;
    u16* kb    = qb + EL;
    u16* vb    = kb + EL;
    u16* virtb = vb + EL;
    float* musig = (float*)(virtb + EL);

    // Scratch inside d_out (134 MB): WtA at [0, 4.7 MB), vt at [8 MB, 75 MB).
    u16* WtA = (u16*)d_out;
    u16* vt  = (u16*)d_out + (1u << 22);   // byte offset 8 MB
    u16* WtC = qb;                          // qb is dead after attn

    const dim3 cgrid(256, 4);

    wt_kernel<<<9216, 256, 0, stream>>>(Wq, WtA);
    conv_mfma_kernel<<<cgrid, 256, 0, stream>>>(x, WtA, qb);
    wt_kernel<<<9216, 256, 0, stream>>>(Wk, WtA);
    conv_mfma_kernel<<<cgrid, 256, 0, stream>>>(x, WtA, kb);
    wt_kernel<<<9216, 256, 0, stream>>>(Wv, WtA);
    conv_mfma_kernel<<<cgrid, 256, 0, stream>>>(x, WtA, vb);

    vt_kernel<<<dim3(256, 32), 256, 0, stream>>>(vb, vt);
    attn_mfma_kernel<<<2048, 256, 0, stream>>>(qb, kb, vt, roi, virtb);
    stats_kernel<<<256, 256, 0, stream>>>(virtb, musig);

    wt_kernel<<<9216, 256, 0, stream>>>(Wc, WtC);
    conv_out_mfma_kernel<<<cgrid, 256, 0, stream>>>(virtb, WtC, x, gam, bet, musig, out);
}

// Round 3
// 1696.902 us; speedup vs baseline: 1.2421x; 1.2421x over previous
//
#include <hip/hip_runtime.h>
#include <hip/hip_bf16.h>

#define NN 256
#define CCH 512
#define TT 4
#define SS 64
#define LL 256

typedef unsigned short u16;
typedef unsigned int u32;

typedef __bf16 bf16_t;
typedef bf16_t bf16x8 __attribute__((ext_vector_type(8)));
typedef float f32x16 __attribute__((ext_vector_type(16)));

__device__ __forceinline__ float bf2f(u32 h){
    return __uint_as_float(h << 16);
}
__device__ __forceinline__ u16 f2bf(float f){
    u32 u = __float_as_uint(f);
    u32 r = u + 0x7fffu + ((u >> 16) & 1u);
    return (u16)(r >> 16);
}
__device__ __forceinline__ bf16x8 ldg8(const u16* p){
    uint4 q = *(const uint4*)p;          // 16B aligned by construction
    return __builtin_bit_cast(bf16x8, q);
}

// ---------------------------------------------------------------------------
// Weight transpose: W[o][c][tap] fp32  ->  Wt[((tap*32 + c/16)*512 + o)*16 + c%16] bf16
// ---------------------------------------------------------------------------
__global__ __launch_bounds__(256) void wt_kernel(
    const float* __restrict__ W, u16* __restrict__ Wt)
{
    const int e = blockIdx.x * 256 + threadIdx.x;     // 0 .. 9*32*512*16-1
    const int cl  = e & 15;
    const int o   = (e >> 4) & 511;
    const int cg  = (e >> 13) & 31;
    const int tap = e >> 18;
    Wt[e] = f2bf(W[((size_t)o * CCH + cg * 16 + cl) * 9 + tap]);
}

// ---------------------------------------------------------------------------
// Implicit-GEMM conv via MFMA 32x32x16 bf16 — cooperative structure (round-1)
// with: LDS c-stride 40 u16 (single conflict-free ds_read_b128 B-frags),
// conflict-free uint4 staging writes, double-buffered LDS with ONE barrier
// per ch-step, stage loads issued before compute (latency hides under MFMA).
// Block: n = blockIdx.x, o-base = blockIdx.y*128.
// Wave (wm = w&1 -> 64 o, wn = w>>1 -> 4 n-tiles); wave w stages plane w.
// ---------------------------------------------------------------------------
__global__ __launch_bounds__(256, 2) void conv_mfma_kernel(
    const float* __restrict__ x, const u16* __restrict__ Wt, u16* __restrict__ outb)
{
    __shared__ u16 lds[2 * 4 * 100 * 40];   // 64 KB: [buf][plane][sp 100][c 40]
    const int tid = threadIdx.x;
    const int n  = blockIdx.x;
    const int ob = blockIdx.y * 128;
    const int lane = tid & 63;
    const int w  = tid >> 6;
    const int wm = w & 1, wn = w >> 1;
    const int h   = lane >> 5;
    const int col = lane & 31;
    const int r  = col >> 3, cc = col & 7;

    // zero once; borders stay 0 = conv padding (staging only writes interior)
    for (int i = tid; i < 16000; i += 256) ((u32*)lds)[i] = 0;

    f32x16 acc[2][4];
    #pragma unroll
    for (int m = 0; m < 2; ++m)
      #pragma unroll
      for (int j = 0; j < 4; ++j)
        #pragma unroll
        for (int e = 0; e < 16; ++e) acc[m][j][e] = 0.f;

    const int g  = lane >> 4;            // c-octet 0..3
    const int sl = lane & 15;            // spatial group (4 s each)

    int bbase[4];
    #pragma unroll
    for (int j = 0; j < 4; ++j){
        const int nt = wn * 4 + j;
        const int p = nt >> 1, sh = nt & 1;
        bbase[j] = (p * 100 + (sh * 4 + r) * 10 + cc) * 40 + h * 8;
    }
    const size_t abase = (size_t)(ob + wm * 64 + col) * 16 + h * 8;

    // wave w stages plane w of the tile
    auto stage_load = [&](int ch, float4* xv){
        const float* xr = x + (((size_t)n * CCH + ch * 32 + g * 8) * TT + w) * SS + sl * 4;
        #pragma unroll
        for (int c2 = 0; c2 < 8; ++c2)
            xv[c2] = *(const float4*)(xr + (size_t)c2 * (TT * SS));
    };
    auto stage_write = [&](int buf, const float4* xv){
        u16* wb = lds + buf * 16000 + w * 4000;
        #pragma unroll
        for (int i = 0; i < 4; ++i){
            const int s = sl * 4 + i;
            const int sp = ((s >> 3) + 1) * 10 + (s & 7) + 1;
            uint4 pw;
            pw.x = (u32)f2bf(((const float*)&xv[0])[i]) | ((u32)f2bf(((const float*)&xv[1])[i]) << 16);
            pw.y = (u32)f2bf(((const float*)&xv[2])[i]) | ((u32)f2bf(((const float*)&xv[3])[i]) << 16);
            pw.z = (u32)f2bf(((const float*)&xv[4])[i]) | ((u32)f2bf(((const float*)&xv[5])[i]) << 16);
            pw.w = (u32)f2bf(((const float*)&xv[6])[i]) | ((u32)f2bf(((const float*)&xv[7])[i]) << 16);
            *(uint4*)&wb[sp * 40 + g * 8] = pw;
        }
    };

    // prologue: stage ch 0 into buf 0
    {
        float4 xv[8];
        stage_load(0, xv);
        __syncthreads();                 // zero-init complete
        stage_write(0, xv);
    }
    __syncthreads();

    for (int ch = 0; ch < 16; ++ch){
        float4 xv[8];
        if (ch < 15) stage_load(ch + 1, xv);       // in flight under compute

        const u16* cb = lds + (ch & 1) * 16000;
        #pragma unroll
        for (int tap = 0; tap < 9; ++tap){
            const int tof = ((tap / 3) * 10 + (tap % 3)) * 40;
            #pragma unroll
            for (int ks = 0; ks < 2; ++ks){
                const size_t ai = (size_t)(tap * 32 + ch * 2 + ks) * 8192 + abase;
                const bf16x8 a0 = ldg8(Wt + ai);
                const bf16x8 a1 = ldg8(Wt + ai + 512);
                bf16x8 bfr[4];
                #pragma unroll
                for (int j = 0; j < 4; ++j)
                    bfr[j] = ldg8(&cb[bbase[j] + tof + ks * 16]);   // ds_read_b128
                #pragma unroll
                for (int j = 0; j < 4; ++j){
                    acc[0][j] = __builtin_amdgcn_mfma_f32_32x32x16_bf16(a0, bfr[j], acc[0][j], 0, 0, 0);
                    acc[1][j] = __builtin_amdgcn_mfma_f32_32x32x16_bf16(a1, bfr[j], acc[1][j], 0, 0, 0);
                }
            }
        }
        if (ch < 15) stage_write((ch + 1) & 1, xv);
        __syncthreads();                 // one barrier per ch-step
    }

    // epilogue: bf16 store to [loc][n][c]
    #pragma unroll
    for (int m = 0; m < 2; ++m){
        #pragma unroll
        for (int j = 0; j < 4; ++j){
            const int nt = wn * 4 + j;
            const int p = nt >> 1, sh = nt & 1;
            const int loc = p * SS + sh * 32 + col;
            u16* orow = outb + ((size_t)loc * NN + n) * CCH + ob + wm * 64 + m * 32;
            #pragma unroll
            for (int g2 = 0; g2 < 4; ++g2){
                uint2 val;
                val.x = (u32)f2bf(acc[m][j][g2 * 4 + 0]) | ((u32)f2bf(acc[m][j][g2 * 4 + 1]) << 16);
                val.y = (u32)f2bf(acc[m][j][g2 * 4 + 2]) | ((u32)f2bf(acc[m][j][g2 * 4 + 3]) << 16);
                *(uint2*)&orow[g2 * 8 + h * 4] = val;
            }
        }
    }
}

// ---------------------------------------------------------------------------
// conv_out: same structure; staging applies GroupNorm+affine+ReLU while
// converting virt; epilogue adds residual x and stores fp32 [n][c][t][s].
// ---------------------------------------------------------------------------
__global__ __launch_bounds__(256, 2) void conv_out_mfma_kernel(
    const u16* __restrict__ virtb, const u16* __restrict__ Wt,
    const float* __restrict__ x, const float* __restrict__ gamma,
    const float* __restrict__ beta, const float* __restrict__ musig,
    float* __restrict__ out)
{
    __shared__ u16 lds[2 * 4 * 100 * 40];
    const int tid = threadIdx.x;
    const int n  = blockIdx.x;
    const int ob = blockIdx.y * 128;
    const int lane = tid & 63;
    const int w  = tid >> 6;
    const int wm = w & 1, wn = w >> 1;
    const int h   = lane >> 5;
    const int col = lane & 31;
    const int r  = col >> 3, cc = col & 7;

    const float mu   = musig[2 * n];
    const float rsig = musig[2 * n + 1];

    for (int i = tid; i < 16000; i += 256) ((u32*)lds)[i] = 0;

    f32x16 acc[2][4];
    #pragma unroll
    for (int m = 0; m < 2; ++m)
      #pragma unroll
      for (int j = 0; j < 4; ++j)
        #pragma unroll
        for (int e = 0; e < 16; ++e) acc[m][j][e] = 0.f;

    const int g  = lane >> 4;
    const int sl = lane & 15;

    int bbase[4];
    #pragma unroll
    for (int j = 0; j < 4; ++j){
        const int nt = wn * 4 + j;
        const int p = nt >> 1, sh = nt & 1;
        bbase[j] = (p * 100 + (sh * 4 + r) * 10 + cc) * 40 + h * 8;
    }
    const size_t abase = (size_t)(ob + wm * 64 + col) * 16 + h * 8;

    auto stage_load = [&](int ch, uint4* vv){
        #pragma unroll
        for (int i = 0; i < 4; ++i){
            const int s = sl * 4 + i;
            vv[i] = *(const uint4*)(virtb + ((size_t)(w * SS + s) * NN + n) * CCH + ch * 32 + g * 8);
        }
    };
    auto stage_write = [&](int ch, int buf, const uint4* vv){
        const float* gp = gamma + ch * 32 + g * 8;
        const float* bp = beta  + ch * 32 + g * 8;
        const float4 ga0 = *(const float4*)gp;
        const float4 ga1 = *(const float4*)(gp + 4);
        const float4 be0 = *(const float4*)bp;
        const float4 be1 = *(const float4*)(bp + 4);
        const float gav[8] = {ga0.x, ga0.y, ga0.z, ga0.w, ga1.x, ga1.y, ga1.z, ga1.w};
        const float bev[8] = {be0.x, be0.y, be0.z, be0.w, be1.x, be1.y, be1.z, be1.w};
        float gsc[8], off[8];
        #pragma unroll
        for (int c2 = 0; c2 < 8; ++c2){
            gsc[c2] = gav[c2] * rsig;
            off[c2] = bev[c2] - mu * rsig * gav[c2];
        }
        u16* wb = lds + buf * 16000 + w * 4000;
        #pragma unroll
        for (int i = 0; i < 4; ++i){
            const int s = sl * 4 + i;
            const int sp = ((s >> 3) + 1) * 10 + (s & 7) + 1;
            const u32 q[4] = {vv[i].x, vv[i].y, vv[i].z, vv[i].w};
            u16 ov[8];
            #pragma unroll
            for (int c2 = 0; c2 < 8; ++c2){
                const u32 half = (c2 & 1) ? (q[c2 >> 1] >> 16) : (q[c2 >> 1] & 0xffffu);
                const float f = fmaxf(bf2f(half) * gsc[c2] + off[c2], 0.f);
                ov[c2] = f2bf(f);
            }
            uint4 pw;
            pw.x = (u32)ov[0] | ((u32)ov[1] << 16);
            pw.y = (u32)ov[2] | ((u32)ov[3] << 16);
            pw.z = (u32)ov[4] | ((u32)ov[5] << 16);
            pw.w = (u32)ov[6] | ((u32)ov[7] << 16);
            *(uint4*)&wb[sp * 40 + g * 8] = pw;
        }
    };

    {
        uint4 vv[4];
        stage_load(0, vv);
        __syncthreads();
        stage_write(0, 0, vv);
    }
    __syncthreads();

    for (int ch = 0; ch < 16; ++ch){
        uint4 vv[4];
        if (ch < 15) stage_load(ch + 1, vv);

        const u16* cb = lds + (ch & 1) * 16000;
        #pragma unroll
        for (int tap = 0; tap < 9; ++tap){
            const int tof = ((tap / 3) * 10 + (tap % 3)) * 40;
            #pragma unroll
            for (int ks = 0; ks < 2; ++ks){
                const size_t ai = (size_t)(tap * 32 + ch * 2 + ks) * 8192 + abase;
                const bf16x8 a0 = ldg8(Wt + ai);
                const bf16x8 a1 = ldg8(Wt + ai + 512);
                bf16x8 bfr[4];
                #pragma unroll
                for (int j = 0; j < 4; ++j)
                    bfr[j] = ldg8(&cb[bbase[j] + tof + ks * 16]);
                #pragma unroll
                for (int j = 0; j < 4; ++j){
                    acc[0][j] = __builtin_amdgcn_mfma_f32_32x32x16_bf16(a0, bfr[j], acc[0][j], 0, 0, 0);
                    acc[1][j] = __builtin_amdgcn_mfma_f32_32x32x16_bf16(a1, bfr[j], acc[1][j], 0, 0, 0);
                }
            }
        }
        if (ch < 15) stage_write(ch + 1, (ch + 1) & 1, vv);
        __syncthreads();
    }

    // epilogue: out = x + conv, fp32 [n][c][t][s]
    #pragma unroll
    for (int m = 0; m < 2; ++m){
        #pragma unroll
        for (int j = 0; j < 4; ++j){
            const int nt = wn * 4 + j;
            const int p = nt >> 1, sh = nt & 1;
            const int s = sh * 32 + col;
            #pragma unroll
            for (int g2 = 0; g2 < 4; ++g2){
                const int o0 = ob + wm * 64 + m * 32 + 8 * g2 + 4 * h;
                #pragma unroll
                for (int rr = 0; rr < 4; ++rr){
                    const size_t oi = (((size_t)n * CCH + o0 + rr) * TT + p) * SS + s;
                    out[oi] = x[oi] + acc[m][j][g2 * 4 + rr];
                }
            }
        }
    }
}

// ---------------------------------------------------------------------------
// V transpose: vb [loc][n][c] -> vt [loc][c][n]  (unchanged)
// ---------------------------------------------------------------------------
__global__ __launch_bounds__(256) void vt_kernel(
    const u16* __restrict__ vb, u16* __restrict__ vt)
{
    __shared__ u16 ts[64][72];
    const int loc = blockIdx.x;
    const int n0 = (blockIdx.y & 3) * 64;
    const int c0 = (blockIdx.y >> 2) * 64;
    const int tid = threadIdx.x;
    const int rr = tid >> 3;          // 0..31
    const int ct = tid & 7;           // col-block / n-block
    #pragma unroll
    for (int q = 0; q < 2; ++q){
        const int row = rr + q * 32;
        const int key = (row & 7) ^ ((row >> 3) & 7);
        const uint4 v = *(const uint4*)(vb + ((size_t)loc * NN + n0 + row) * CCH + c0 + ct * 8);
        *(uint4*)&ts[row][(ct ^ key) << 3] = v;
    }
    __syncthreads();
    #pragma unroll
    for (int q = 0; q < 2; ++q){
        const int c = rr + q * 32;    // local c row of vt
        u16 tmp[8];
        #pragma unroll
        for (int e = 0; e < 8; ++e){
            const int n = ct * 8 + e;
            const int key = (n & 7) ^ ((n >> 3) & 7);   // = e ^ ct
            tmp[e] = ts[n][(((c >> 3) ^ key) << 3) + (c & 7)];
        }
        uint4 o;
        o.x = (u32)tmp[0] | ((u32)tmp[1] << 16);
        o.y = (u32)tmp[2] | ((u32)tmp[3] << 16);
        o.z = (u32)tmp[4] | ((u32)tmp[5] << 16);
        o.w = (u32)tmp[6] | ((u32)tmp[7] << 16);
        *(uint4*)(vt + ((size_t)loc * CCH + c0 + c) * NN + n0 + ct * 8) = o;
    }
}

// ---------------------------------------------------------------------------
// MFMA attention (unchanged).
// ---------------------------------------------------------------------------
__global__ __launch_bounds__(256, 3) void attn_mfma_kernel(
    const u16* __restrict__ qb, const u16* __restrict__ kb,
    const u16* __restrict__ vt, const int* __restrict__ roi,
    u16* __restrict__ virtb)
{
    __shared__ float Srow[32][264];      // 33.8 KB
    __shared__ u16 Pfrag[16 * 64 * 8];   // 16 KB, A-frag layout for PV
    __shared__ int roi_s[256];

    const int bid = blockIdx.x;
    const int loc = ((bid >> 6) << 3) | (bid & 7);   // XCD-coherent decode
    const int it  = (bid >> 3) & 7;
    const int i0  = it * 32;
    const int tid = threadIdx.x;
    const int lane = tid & 63;
    const int w   = tid >> 6;
    const int h   = lane >> 5;
    const int col = lane & 31;

    roi_s[tid] = roi[tid];

    // ---- Phase 1: QK^T, wave w owns j = w*64 .. w*64+63 ----
    f32x16 acc0, acc1;
    #pragma unroll
    for (int e = 0; e < 16; ++e){ acc0[e] = 0.f; acc1[e] = 0.f; }

    const u16* qp = qb + ((size_t)loc * NN + i0 + col) * CCH + h * 8;
    const u16* kp = kb + ((size_t)loc * NN + w * 64 + col) * CCH + h * 8;

    #pragma unroll 4
    for (int kc = 0; kc < 32; ++kc){
        const bf16x8 a  = ldg8(qp + kc * 16);
        const bf16x8 b0 = ldg8(kp + kc * 16);
        const bf16x8 b1 = ldg8(kp + 32 * CCH + kc * 16);
        acc0 = __builtin_amdgcn_mfma_f32_32x32x16_bf16(a, b0, acc0, 0, 0, 0);
        acc1 = __builtin_amdgcn_mfma_f32_32x32x16_bf16(a, b1, acc1, 0, 0, 0);
    }

    #pragma unroll
    for (int e = 0; e < 16; ++e){
        const int r = (e & 3) + 8 * (e >> 2) + 4 * h;
        Srow[r][w * 64 + col]      = acc0[e];
        Srow[r][w * 64 + 32 + col] = acc1[e];
    }
    __syncthreads();

    // ---- Phase 2: masked softmax, 8 threads per row ----
    {
        const int row = tid >> 3, u = tid & 7;
        const int myroi = roi_s[i0 + row];
        const float scale = 0.04419417382415922f;
        float ev[32];
        float mx = -1e30f;
        #pragma unroll
        for (int g = 0; g < 8; ++g){
            const float4 s4 = *(const float4*)&Srow[row][u * 4 + g * 32];
            const float ss[4] = {s4.x, s4.y, s4.z, s4.w};
            #pragma unroll
            for (int q = 0; q < 4; ++q){
                const int j = u * 4 + g * 32 + q;
                const float xv = (roi_s[j] == myroi) ? ss[q] * scale : -1e30f;
                ev[g * 4 + q] = xv;
                mx = fmaxf(mx, xv);
            }
        }
        mx = fmaxf(mx, __shfl_xor(mx, 1));
        mx = fmaxf(mx, __shfl_xor(mx, 2));
        mx = fmaxf(mx, __shfl_xor(mx, 4));
        float ssum = 0.f;
        #pragma unroll
        for (int q2 = 0; q2 < 32; ++q2){
            const float e2 = (ev[q2] > -1e29f) ? __expf(ev[q2] - mx) : 0.f;
            ev[q2] = e2;
            ssum += e2;
        }
        ssum += __shfl_xor(ssum, 1);
        ssum += __shfl_xor(ssum, 2);
        ssum += __shfl_xor(ssum, 4);
        const float rinv = 1.f / ssum;
        #pragma unroll
        for (int g = 0; g < 8; ++g){
            const int t    = 2 * g + (u >> 2);
            const int half = (u >> 1) & 1;
            const int e0   = (u & 1) * 4;
            uint2 pw;
            pw.x = (u32)f2bf(ev[g * 4 + 0] * rinv) | ((u32)f2bf(ev[g * 4 + 1] * rinv) << 16);
            pw.y = (u32)f2bf(ev[g * 4 + 2] * rinv) | ((u32)f2bf(ev[g * 4 + 3] * rinv) << 16);
            *(uint2*)&Pfrag[((t * 64 + half * 32 + row) << 3) + e0] = pw;
        }
    }
    __syncthreads();

    // ---- Phase 3: PV, wave w owns c = w*128 .. w*128+127 ----
    f32x16 pacc[4];
    #pragma unroll
    for (int jn = 0; jn < 4; ++jn)
        #pragma unroll
        for (int e = 0; e < 16; ++e) pacc[jn][e] = 0.f;

    const u16* vp = vt + ((size_t)loc * CCH + w * 128 + col) * NN + h * 8;
    #pragma unroll 2
    for (int t = 0; t < 16; ++t){
        const bf16x8 pa = ldg8(&Pfrag[(t * 64 + lane) << 3]);
        #pragma unroll
        for (int jn = 0; jn < 4; ++jn){
            const bf16x8 bv = ldg8(vp + (size_t)(jn * 32) * NN + t * 16);
            pacc[jn] = __builtin_amdgcn_mfma_f32_32x32x16_bf16(pa, bv, pacc[jn], 0, 0, 0);
        }
    }

    u16* op = virtb + ((size_t)loc * NN + i0) * CCH + w * 128 + col;
    #pragma unroll
    for (int jn = 0; jn < 4; ++jn){
        #pragma unroll
        for (int e = 0; e < 16; ++e){
            const int r = (e & 3) + 8 * (e >> 2) + 4 * h;
            op[(size_t)r * CCH + jn * 32] = f2bf(pacc[jn][e]);
        }
    }
}

// ---------------------------------------------------------------------------
// GroupNorm stats per sample.
// ---------------------------------------------------------------------------
__global__ __launch_bounds__(256) void stats_kernel(
    const u16* __restrict__ virtb, float* __restrict__ musig)
{
    const int n = blockIdx.x;
    const int tid = threadIdx.x;
    float s = 0.f, q = 0.f;
    for (int loc = 0; loc < LL; ++loc){
        const u32 v = *(const u32*)(virtb + ((size_t)loc * NN + n) * CCH + 2 * tid);
        const float a = bf2f(v & 0xffffu);
        const float b = bf2f(v >> 16);
        s += a + b;
        q += a * a + b * b;
    }
    #pragma unroll
    for (int off = 1; off < 64; off <<= 1){
        s += __shfl_xor(s, off);
        q += __shfl_xor(q, off);
    }
    __shared__ float red[8];
    const int wave = tid >> 6;
    if ((tid & 63) == 0){ red[wave * 2] = s; red[wave * 2 + 1] = q; }
    __syncthreads();
    if (tid == 0){
        const float S = red[0] + red[2] + red[4] + red[6];
        const float Q = red[1] + red[3] + red[5] + red[7];
        const float inv = 1.f / 131072.f;
        const float mval = S * inv;
        const float var = Q * inv - mval * mval;
        musig[2 * n]     = mval;
        musig[2 * n + 1] = rsqrtf(var + 1e-5f);
    }
}

__global__ void sentinel_kernel(float* out){
    const size_t i = (size_t)blockIdx.x * 256 + threadIdx.x;
    out[i] = 1.0e9f;
}

extern "C" void kernel_launch(void* const* d_in, const int* in_sizes, int n_in,
                              void* d_out, int out_size, void* d_ws, size_t ws_size,
                              hipStream_t stream)
{
    (void)in_sizes; (void)n_in; (void)out_size;
    const float* x   = (const float*)d_in[0];
    const int*   roi = (const int*)d_in[1];
    const float* Wq  = (const float*)d_in[2];
    const float* Wk  = (const float*)d_in[3];
    const float* Wv  = (const float*)d_in[4];
    const float* Wc  = (const float*)d_in[5];
    const float* gam = (const float*)d_in[6];
    const float* bet = (const float*)d_in[7];
    float* out = (float*)d_out;

    const size_t EL = 33554432ull;                 // N*C*T*H*W
    const size_t need = EL * 2ull * 4ull + 2048ull;
    if (ws_size < need){
        sentinel_kernel<<<131072, 256, 0, stream>>>(out);
        return;
    }
    u16* qb    = (u16*)d_ws;
    u16* kb    = qb + EL;
    u16* vb    = kb + EL;
    u16* virtb = vb + EL;
    float* musig = (float*)(virtb + EL);

    // Scratch inside d_out (134 MB): WtA at [0, 4.7 MB), vt at [8 MB, 75 MB).
    u16* WtA = (u16*)d_out;
    u16* vt  = (u16*)d_out + (1u << 22);   // byte offset 8 MB
    u16* WtC = qb;                          // qb is dead after attn

    const dim3 cgrid(256, 4);

    wt_kernel<<<9216, 256, 0, stream>>>(Wq, WtA);
    conv_mfma_kernel<<<cgrid, 256, 0, stream>>>(x, WtA, qb);
    wt_kernel<<<9216, 256, 0, stream>>>(Wk, WtA);
    conv_mfma_kernel<<<cgrid, 256, 0, stream>>>(x, WtA, kb);
    wt_kernel<<<9216, 256, 0, stream>>>(Wv, WtA);
    conv_mfma_kernel<<<cgrid, 256, 0, stream>>>(x, WtA, vb);

    vt_kernel<<<dim3(256, 32), 256, 0, stream>>>(vb, vt);
    attn_mfma_kernel<<<2048, 256, 0, stream>>>(qb, kb, vt, roi, virtb);
    stats_kernel<<<256, 256, 0, stream>>>(virtb, musig);

    wt_kernel<<<9216, 256, 0, stream>>>(Wc, WtC);
    conv_out_mfma_kernel<<<cgrid, 256, 0, stream>>>(virtb, WtC, x, gam, bet, musig, out);
}

// Round 4
// 1595.450 us; speedup vs baseline: 1.3211x; 1.0636x over previous
//
#include <hip/hip_runtime.h>
#include <hip/hip_bf16.h>

#define NN 256
#define CCH 512
#define TT 4
#define SS 64
#define LL 256

typedef unsigned short u16;
typedef unsigned int u32;

typedef __bf16 bf16_t;
typedef bf16_t bf16x8 __attribute__((ext_vector_type(8)));
typedef float f32x16 __attribute__((ext_vector_type(16)));

__device__ __forceinline__ float bf2f(u32 h){
    return __uint_as_float(h << 16);
}
__device__ __forceinline__ u16 f2bf(float f){
    u32 u = __float_as_uint(f);
    u32 r = u + 0x7fffu + ((u >> 16) & 1u);
    return (u16)(r >> 16);
}
__device__ __forceinline__ bf16x8 ldg8(const u16* p){
    uint4 q = *(const uint4*)p;          // 16B aligned by construction
    return __builtin_bit_cast(bf16x8, q);
}
__device__ __forceinline__ void gload_lds16(const u16* g, u16* l){
    __builtin_amdgcn_global_load_lds(
        (const __attribute__((address_space(1))) void*)g,
        (__attribute__((address_space(3))) void*)l, 16, 0, 0);
}

// ---------------------------------------------------------------------------
// Weight transpose: W[o][c][tap] fp32  ->  Wt[((tap*32 + c/16)*512 + o)*16 + c%16] bf16
// ---------------------------------------------------------------------------
__global__ __launch_bounds__(256) void wt_kernel(
    const float* __restrict__ W, u16* __restrict__ Wt)
{
    const int e = blockIdx.x * 256 + threadIdx.x;     // 0 .. 9*32*512*16-1
    const int cl  = e & 15;
    const int o   = (e >> 4) & 511;
    const int cg  = (e >> 13) & 31;
    const int tap = e >> 18;
    Wt[e] = f2bf(W[((size_t)o * CCH + cg * 16 + cl) * 9 + tap]);
}

// ---------------------------------------------------------------------------
// xpad: x fp32 [n][c][t][s] -> bf16 conv tiles xpad[(n*16+ch)*12800 u16]:
// [p4][sp100][slot4][8ch], slot = cb ^ (sp&3) (bank swizzle baked into global),
// borders (10x10 frame) zeroed = conv padding.
// ---------------------------------------------------------------------------
__global__ __launch_bounds__(256) void xpad_kernel(
    const float* __restrict__ x, u16* __restrict__ xpad)
{
    const int n  = blockIdx.x;
    const int ch = blockIdx.y;
    const int tid = threadIdx.x;
    const int p  = tid >> 6;
    const int cb = (tid >> 4) & 3;
    const int s4 = (tid & 15) << 2;
    u16* tile = xpad + ((size_t)n * 16 + ch) * 12800;

    // interior
    const float* xr = x + (((size_t)n * CCH + ch * 32 + cb * 8) * TT + p) * SS + s4;
    float4 v[8];
    #pragma unroll
    for (int c2 = 0; c2 < 8; ++c2)
        v[c2] = *(const float4*)(xr + (size_t)c2 * (TT * SS));
    #pragma unroll
    for (int i = 0; i < 4; ++i){
        const int s = s4 + i;
        const int sp = ((s >> 3) + 1) * 10 + (s & 7) + 1;
        const int q = cb ^ (sp & 3);
        uint4 pw;
        pw.x = (u32)f2bf(((const float*)&v[0])[i]) | ((u32)f2bf(((const float*)&v[1])[i]) << 16);
        pw.y = (u32)f2bf(((const float*)&v[2])[i]) | ((u32)f2bf(((const float*)&v[3])[i]) << 16);
        pw.z = (u32)f2bf(((const float*)&v[4])[i]) | ((u32)f2bf(((const float*)&v[5])[i]) << 16);
        pw.w = (u32)f2bf(((const float*)&v[6])[i]) | ((u32)f2bf(((const float*)&v[7])[i]) << 16);
        *(uint4*)&tile[p * 3200 + sp * 32 + q * 8] = pw;
    }
    // borders: per plane 36 sp x 4 slots = 144 chunks; 4 planes = 576
    for (int bt = tid; bt < 576; bt += 256){
        const int pp   = bt / 144;
        const int bb   = bt % 144;
        const int bi   = bb >> 2;
        const int slot = bb & 3;
        int sp;
        if (bi < 10)      sp = bi;
        else if (bi < 20) sp = 90 + (bi - 10);
        else { const int k = (bi - 20) >> 1; sp = (k + 1) * 10 + ((bi - 20) & 1) * 9; }
        uint4 z; z.x = 0; z.y = 0; z.z = 0; z.w = 0;
        *(uint4*)&tile[pp * 3200 + sp * 32 + slot * 8] = z;
    }
}

// ---------------------------------------------------------------------------
// virtn: GroupNorm+affine+ReLU(virtb) -> same tile format as xpad.
// ---------------------------------------------------------------------------
__global__ __launch_bounds__(256) void virtn_kernel(
    const u16* __restrict__ virtb, const float* __restrict__ musig,
    const float* __restrict__ gamma, const float* __restrict__ beta,
    u16* __restrict__ vn)
{
    const int n  = blockIdx.x;
    const int ch = blockIdx.y;
    const int tid = threadIdx.x;
    const int p  = tid >> 6;
    const int cb = (tid >> 4) & 3;
    const int s4 = (tid & 15) << 2;
    u16* tile = vn + ((size_t)n * 16 + ch) * 12800;

    const float mu   = musig[2 * n];
    const float rsig = musig[2 * n + 1];
    const int c0 = ch * 32 + cb * 8;
    const float4 ga0 = *(const float4*)(gamma + c0);
    const float4 ga1 = *(const float4*)(gamma + c0 + 4);
    const float4 be0 = *(const float4*)(beta + c0);
    const float4 be1 = *(const float4*)(beta + c0 + 4);
    const float gav[8] = {ga0.x, ga0.y, ga0.z, ga0.w, ga1.x, ga1.y, ga1.z, ga1.w};
    const float bev[8] = {be0.x, be0.y, be0.z, be0.w, be1.x, be1.y, be1.z, be1.w};
    float gsc[8], off[8];
    #pragma unroll
    for (int c2 = 0; c2 < 8; ++c2){
        gsc[c2] = gav[c2] * rsig;
        off[c2] = bev[c2] - mu * rsig * gav[c2];
    }

    #pragma unroll
    for (int i = 0; i < 4; ++i){
        const int s = s4 + i;
        const int loc = p * SS + s;
        const uint4 wv = *(const uint4*)(virtb + ((size_t)loc * NN + n) * CCH + c0);
        const u32 q4[4] = {wv.x, wv.y, wv.z, wv.w};
        u16 ov[8];
        #pragma unroll
        for (int c2 = 0; c2 < 8; ++c2){
            const u32 half = (c2 & 1) ? (q4[c2 >> 1] >> 16) : (q4[c2 >> 1] & 0xffffu);
            ov[c2] = f2bf(fmaxf(bf2f(half) * gsc[c2] + off[c2], 0.f));
        }
        const int sp = ((s >> 3) + 1) * 10 + (s & 7) + 1;
        const int q = cb ^ (sp & 3);
        uint4 pw;
        pw.x = (u32)ov[0] | ((u32)ov[1] << 16);
        pw.y = (u32)ov[2] | ((u32)ov[3] << 16);
        pw.z = (u32)ov[4] | ((u32)ov[5] << 16);
        pw.w = (u32)ov[6] | ((u32)ov[7] << 16);
        *(uint4*)&tile[p * 3200 + sp * 32 + q * 8] = pw;
    }
    for (int bt = tid; bt < 576; bt += 256){
        const int pp   = bt / 144;
        const int bb   = bt % 144;
        const int bi   = bb >> 2;
        const int slot = bb & 3;
        int sp;
        if (bi < 10)      sp = bi;
        else if (bi < 20) sp = 90 + (bi - 10);
        else { const int k = (bi - 20) >> 1; sp = (k + 1) * 10 + ((bi - 20) & 1) * 9; }
        uint4 z; z.x = 0; z.y = 0; z.z = 0; z.w = 0;
        *(uint4*)&tile[pp * 3200 + sp * 32 + slot * 8] = z;
    }
}

// ---------------------------------------------------------------------------
// Implicit-GEMM conv via MFMA 32x32x16 bf16.
// Staging = global_load_lds DMA from pre-padded, pre-swizzled bf16 tiles
// (zero staging VGPRs / VALU / ds_writes). Double-buffered, 1 barrier/ch-step.
// B-frag ds_read_b128 with slot = cb^(sp&3): 8 lanes per 16B slot, conflict-free.
// Block decode XCD-chunked: 4 o-blocks of one n co-reside on one XCD.
// ---------------------------------------------------------------------------
__global__ __launch_bounds__(256, 2) void conv_mfma_kernel(
    const u16* __restrict__ xp, const u16* __restrict__ Wt, u16* __restrict__ outb)
{
    __shared__ u16 lds[2 * 12800];       // 50 KB
    const int bid = blockIdx.x;
    const int wk  = (bid & 7) * 128 + (bid >> 3);   // XCD-chunked (1024 % 8 == 0)
    const int n  = wk >> 2;
    const int ob = (wk & 3) * 128;
    const int tid = threadIdx.x;
    const int lane = tid & 63;
    const int w  = tid >> 6;
    const int wm = w & 1, wn = w >> 1;
    const int h   = lane >> 5;
    const int col = lane & 31;
    const int r  = col >> 3, cc = col & 7;

    f32x16 acc[2][4];
    #pragma unroll
    for (int m = 0; m < 2; ++m)
      #pragma unroll
      for (int j = 0; j < 4; ++j)
        #pragma unroll
        for (int e = 0; e < 16; ++e) acc[m][j][e] = 0.f;

    int pb[4], sp0[4];
    #pragma unroll
    for (int j = 0; j < 4; ++j){
        const int nt = wn * 4 + j;
        pb[j]  = (nt >> 1) * 3200;
        sp0[j] = ((nt & 1) * 4 + r) * 10 + cc;
    }
    const size_t abase = (size_t)(ob + wm * 64 + col) * 16 + h * 8;
    const u16* srcn = xp + (size_t)n * (16 * 12800) + lane * 8;

    auto stage = [&](int ch, int buf){
        const u16* g = srcn + (size_t)ch * 12800;
        for (int i = w; i < 25; i += 4)
            gload_lds16(g + i * 512, &lds[buf * 12800 + i * 512]);
    };

    stage(0, 0);
    __syncthreads();

    for (int ch = 0; ch < 16; ++ch){
        if (ch < 15) stage(ch + 1, (ch + 1) & 1);
        const u16* cbuf = &lds[(ch & 1) * 12800];
        #pragma unroll
        for (int tap = 0; tap < 9; ++tap){
            const int T = (tap / 3) * 10 + (tap % 3);
            #pragma unroll
            for (int ks = 0; ks < 2; ++ks){
                const size_t ai = (size_t)(tap * 32 + ch * 2 + ks) * 8192 + abase;
                const bf16x8 a0 = ldg8(Wt + ai);
                const bf16x8 a1 = ldg8(Wt + ai + 512);
                bf16x8 bfr[4];
                #pragma unroll
                for (int j = 0; j < 4; ++j){
                    const int sp = sp0[j] + T;
                    const int idx = pb[j] + sp * 32 + ((((ks << 1) | h) ^ (sp & 3)) << 3);
                    bfr[j] = ldg8(&cbuf[idx]);
                }
                #pragma unroll
                for (int j = 0; j < 4; ++j){
                    acc[0][j] = __builtin_amdgcn_mfma_f32_32x32x16_bf16(a0, bfr[j], acc[0][j], 0, 0, 0);
                    acc[1][j] = __builtin_amdgcn_mfma_f32_32x32x16_bf16(a1, bfr[j], acc[1][j], 0, 0, 0);
                }
            }
        }
        __syncthreads();
    }

    // epilogue: bf16 store to [loc][n][c]
    #pragma unroll
    for (int m = 0; m < 2; ++m){
        #pragma unroll
        for (int j = 0; j < 4; ++j){
            const int nt = wn * 4 + j;
            const int p = nt >> 1, sh = nt & 1;
            const int loc = p * SS + sh * 32 + col;
            u16* orow = outb + ((size_t)loc * NN + n) * CCH + ob + wm * 64 + m * 32;
            #pragma unroll
            for (int g2 = 0; g2 < 4; ++g2){
                uint2 val;
                val.x = (u32)f2bf(acc[m][j][g2 * 4 + 0]) | ((u32)f2bf(acc[m][j][g2 * 4 + 1]) << 16);
                val.y = (u32)f2bf(acc[m][j][g2 * 4 + 2]) | ((u32)f2bf(acc[m][j][g2 * 4 + 3]) << 16);
                *(uint2*)&orow[g2 * 8 + h * 4] = val;
            }
        }
    }
}

// ---------------------------------------------------------------------------
// conv_out: identical structure (reads virtn tiles); epilogue adds residual x,
// stores fp32 [n][c][t][s].
// ---------------------------------------------------------------------------
__global__ __launch_bounds__(256, 2) void conv_out_mfma_kernel(
    const u16* __restrict__ vnp, const u16* __restrict__ Wt,
    const float* __restrict__ x, float* __restrict__ out)
{
    __shared__ u16 lds[2 * 12800];
    const int bid = blockIdx.x;
    const int wk  = (bid & 7) * 128 + (bid >> 3);
    const int n  = wk >> 2;
    const int ob = (wk & 3) * 128;
    const int tid = threadIdx.x;
    const int lane = tid & 63;
    const int w  = tid >> 6;
    const int wm = w & 1, wn = w >> 1;
    const int h   = lane >> 5;
    const int col = lane & 31;
    const int r  = col >> 3, cc = col & 7;

    f32x16 acc[2][4];
    #pragma unroll
    for (int m = 0; m < 2; ++m)
      #pragma unroll
      for (int j = 0; j < 4; ++j)
        #pragma unroll
        for (int e = 0; e < 16; ++e) acc[m][j][e] = 0.f;

    int pb[4], sp0[4];
    #pragma unroll
    for (int j = 0; j < 4; ++j){
        const int nt = wn * 4 + j;
        pb[j]  = (nt >> 1) * 3200;
        sp0[j] = ((nt & 1) * 4 + r) * 10 + cc;
    }
    const size_t abase = (size_t)(ob + wm * 64 + col) * 16 + h * 8;
    const u16* srcn = vnp + (size_t)n * (16 * 12800) + lane * 8;

    auto stage = [&](int ch, int buf){
        const u16* g = srcn + (size_t)ch * 12800;
        for (int i = w; i < 25; i += 4)
            gload_lds16(g + i * 512, &lds[buf * 12800 + i * 512]);
    };

    stage(0, 0);
    __syncthreads();

    for (int ch = 0; ch < 16; ++ch){
        if (ch < 15) stage(ch + 1, (ch + 1) & 1);
        const u16* cbuf = &lds[(ch & 1) * 12800];
        #pragma unroll
        for (int tap = 0; tap < 9; ++tap){
            const int T = (tap / 3) * 10 + (tap % 3);
            #pragma unroll
            for (int ks = 0; ks < 2; ++ks){
                const size_t ai = (size_t)(tap * 32 + ch * 2 + ks) * 8192 + abase;
                const bf16x8 a0 = ldg8(Wt + ai);
                const bf16x8 a1 = ldg8(Wt + ai + 512);
                bf16x8 bfr[4];
                #pragma unroll
                for (int j = 0; j < 4; ++j){
                    const int sp = sp0[j] + T;
                    const int idx = pb[j] + sp * 32 + ((((ks << 1) | h) ^ (sp & 3)) << 3);
                    bfr[j] = ldg8(&cbuf[idx]);
                }
                #pragma unroll
                for (int j = 0; j < 4; ++j){
                    acc[0][j] = __builtin_amdgcn_mfma_f32_32x32x16_bf16(a0, bfr[j], acc[0][j], 0, 0, 0);
                    acc[1][j] = __builtin_amdgcn_mfma_f32_32x32x16_bf16(a1, bfr[j], acc[1][j], 0, 0, 0);
                }
            }
        }
        __syncthreads();
    }

    // epilogue: out = x + conv, fp32 [n][c][t][s]
    #pragma unroll
    for (int m = 0; m < 2; ++m){
        #pragma unroll
        for (int j = 0; j < 4; ++j){
            const int nt = wn * 4 + j;
            const int p = nt >> 1, sh = nt & 1;
            const int s = sh * 32 + col;
            #pragma unroll
            for (int g2 = 0; g2 < 4; ++g2){
                const int o0 = ob + wm * 64 + m * 32 + 8 * g2 + 4 * h;
                #pragma unroll
                for (int rr = 0; rr < 4; ++rr){
                    const size_t oi = (((size_t)n * CCH + o0 + rr) * TT + p) * SS + s;
                    out[oi] = x[oi] + acc[m][j][g2 * 4 + rr];
                }
            }
        }
    }
}

// ---------------------------------------------------------------------------
// V transpose: vb [loc][n][c] -> vt [loc][c][n]  (unchanged)
// ---------------------------------------------------------------------------
__global__ __launch_bounds__(256) void vt_kernel(
    const u16* __restrict__ vb, u16* __restrict__ vt)
{
    __shared__ u16 ts[64][72];
    const int loc = blockIdx.x;
    const int n0 = (blockIdx.y & 3) * 64;
    const int c0 = (blockIdx.y >> 2) * 64;
    const int tid = threadIdx.x;
    const int rr = tid >> 3;          // 0..31
    const int ct = tid & 7;           // col-block / n-block
    #pragma unroll
    for (int q = 0; q < 2; ++q){
        const int row = rr + q * 32;
        const int key = (row & 7) ^ ((row >> 3) & 7);
        const uint4 v = *(const uint4*)(vb + ((size_t)loc * NN + n0 + row) * CCH + c0 + ct * 8);
        *(uint4*)&ts[row][(ct ^ key) << 3] = v;
    }
    __syncthreads();
    #pragma unroll
    for (int q = 0; q < 2; ++q){
        const int c = rr + q * 32;    // local c row of vt
        u16 tmp[8];
        #pragma unroll
        for (int e = 0; e < 8; ++e){
            const int nn = ct * 8 + e;
            const int key = (nn & 7) ^ ((nn >> 3) & 7);
            tmp[e] = ts[nn][(((c >> 3) ^ key) << 3) + (c & 7)];
        }
        uint4 o;
        o.x = (u32)tmp[0] | ((u32)tmp[1] << 16);
        o.y = (u32)tmp[2] | ((u32)tmp[3] << 16);
        o.z = (u32)tmp[4] | ((u32)tmp[5] << 16);
        o.w = (u32)tmp[6] | ((u32)tmp[7] << 16);
        *(uint4*)(vt + ((size_t)loc * CCH + c0 + c) * NN + n0 + ct * 8) = o;
    }
}

// ---------------------------------------------------------------------------
// MFMA attention (unchanged).
// ---------------------------------------------------------------------------
__global__ __launch_bounds__(256, 3) void attn_mfma_kernel(
    const u16* __restrict__ qb, const u16* __restrict__ kb,
    const u16* __restrict__ vt, const int* __restrict__ roi,
    u16* __restrict__ virtb)
{
    __shared__ float Srow[32][264];
    __shared__ u16 Pfrag[16 * 64 * 8];
    __shared__ int roi_s[256];

    const int bid = blockIdx.x;
    const int loc = ((bid >> 6) << 3) | (bid & 7);   // XCD-coherent decode
    const int it  = (bid >> 3) & 7;
    const int i0  = it * 32;
    const int tid = threadIdx.x;
    const int lane = tid & 63;
    const int w   = tid >> 6;
    const int h   = lane >> 5;
    const int col = lane & 31;

    roi_s[tid] = roi[tid];

    f32x16 acc0, acc1;
    #pragma unroll
    for (int e = 0; e < 16; ++e){ acc0[e] = 0.f; acc1[e] = 0.f; }

    const u16* qp = qb + ((size_t)loc * NN + i0 + col) * CCH + h * 8;
    const u16* kp = kb + ((size_t)loc * NN + w * 64 + col) * CCH + h * 8;

    #pragma unroll 4
    for (int kc = 0; kc < 32; ++kc){
        const bf16x8 a  = ldg8(qp + kc * 16);
        const bf16x8 b0 = ldg8(kp + kc * 16);
        const bf16x8 b1 = ldg8(kp + 32 * CCH + kc * 16);
        acc0 = __builtin_amdgcn_mfma_f32_32x32x16_bf16(a, b0, acc0, 0, 0, 0);
        acc1 = __builtin_amdgcn_mfma_f32_32x32x16_bf16(a, b1, acc1, 0, 0, 0);
    }

    #pragma unroll
    for (int e = 0; e < 16; ++e){
        const int r = (e & 3) + 8 * (e >> 2) + 4 * h;
        Srow[r][w * 64 + col]      = acc0[e];
        Srow[r][w * 64 + 32 + col] = acc1[e];
    }
    __syncthreads();

    {
        const int row = tid >> 3, u = tid & 7;
        const int myroi = roi_s[i0 + row];
        const float scale = 0.04419417382415922f;
        float ev[32];
        float mx = -1e30f;
        #pragma unroll
        for (int g = 0; g < 8; ++g){
            const float4 s4 = *(const float4*)&Srow[row][u * 4 + g * 32];
            const float ss[4] = {s4.x, s4.y, s4.z, s4.w};
            #pragma unroll
            for (int q = 0; q < 4; ++q){
                const int j = u * 4 + g * 32 + q;
                const float xv = (roi_s[j] == myroi) ? ss[q] * scale : -1e30f;
                ev[g * 4 + q] = xv;
                mx = fmaxf(mx, xv);
            }
        }
        mx = fmaxf(mx, __shfl_xor(mx, 1));
        mx = fmaxf(mx, __shfl_xor(mx, 2));
        mx = fmaxf(mx, __shfl_xor(mx, 4));
        float ssum = 0.f;
        #pragma unroll
        for (int q2 = 0; q2 < 32; ++q2){
            const float e2 = (ev[q2] > -1e29f) ? __expf(ev[q2] - mx) : 0.f;
            ev[q2] = e2;
            ssum += e2;
        }
        ssum += __shfl_xor(ssum, 1);
        ssum += __shfl_xor(ssum, 2);
        ssum += __shfl_xor(ssum, 4);
        const float rinv = 1.f / ssum;
        #pragma unroll
        for (int g = 0; g < 8; ++g){
            const int t    = 2 * g + (u >> 2);
            const int half = (u >> 1) & 1;
            const int e0   = (u & 1) * 4;
            uint2 pw;
            pw.x = (u32)f2bf(ev[g * 4 + 0] * rinv) | ((u32)f2bf(ev[g * 4 + 1] * rinv) << 16);
            pw.y = (u32)f2bf(ev[g * 4 + 2] * rinv) | ((u32)f2bf(ev[g * 4 + 3] * rinv) << 16);
            *(uint2*)&Pfrag[((t * 64 + half * 32 + row) << 3) + e0] = pw;
        }
    }
    __syncthreads();

    f32x16 pacc[4];
    #pragma unroll
    for (int jn = 0; jn < 4; ++jn)
        #pragma unroll
        for (int e = 0; e < 16; ++e) pacc[jn][e] = 0.f;

    const u16* vp = vt + ((size_t)loc * CCH + w * 128 + col) * NN + h * 8;
    #pragma unroll 2
    for (int t = 0; t < 16; ++t){
        const bf16x8 pa = ldg8(&Pfrag[(t * 64 + lane) << 3]);
        #pragma unroll
        for (int jn = 0; jn < 4; ++jn){
            const bf16x8 bv = ldg8(vp + (size_t)(jn * 32) * NN + t * 16);
            pacc[jn] = __builtin_amdgcn_mfma_f32_32x32x16_bf16(pa, bv, pacc[jn], 0, 0, 0);
        }
    }

    u16* op = virtb + ((size_t)loc * NN + i0) * CCH + w * 128 + col;
    #pragma unroll
    for (int jn = 0; jn < 4; ++jn){
        #pragma unroll
        for (int e = 0; e < 16; ++e){
            const int r = (e & 3) + 8 * (e >> 2) + 4 * h;
            op[(size_t)r * CCH + jn * 32] = f2bf(pacc[jn][e]);
        }
    }
}

// ---------------------------------------------------------------------------
// GroupNorm stats per sample.
// ---------------------------------------------------------------------------
__global__ __launch_bounds__(256) void stats_kernel(
    const u16* __restrict__ virtb, float* __restrict__ musig)
{
    const int n = blockIdx.x;
    const int tid = threadIdx.x;
    float s = 0.f, q = 0.f;
    for (int loc = 0; loc < LL; ++loc){
        const u32 v = *(const u32*)(virtb + ((size_t)loc * NN + n) * CCH + 2 * tid);
        const float a = bf2f(v & 0xffffu);
        const float b = bf2f(v >> 16);
        s += a + b;
        q += a * a + b * b;
    }
    #pragma unroll
    for (int off = 1; off < 64; off <<= 1){
        s += __shfl_xor(s, off);
        q += __shfl_xor(q, off);
    }
    __shared__ float red[8];
    const int wave = tid >> 6;
    if ((tid & 63) == 0){ red[wave * 2] = s; red[wave * 2 + 1] = q; }
    __syncthreads();
    if (tid == 0){
        const float S = red[0] + red[2] + red[4] + red[6];
        const float Q = red[1] + red[3] + red[5] + red[7];
        const float inv = 1.f / 131072.f;
        const float mval = S * inv;
        const float var = Q * inv - mval * mval;
        musig[2 * n]     = mval;
        musig[2 * n + 1] = rsqrtf(var + 1e-5f);
    }
}

__global__ void sentinel_kernel(float* out){
    const size_t i = (size_t)blockIdx.x * 256 + threadIdx.x;
    out[i] = 1.0e9f;
}

extern "C" void kernel_launch(void* const* d_in, const int* in_sizes, int n_in,
                              void* d_out, int out_size, void* d_ws, size_t ws_size,
                              hipStream_t stream)
{
    (void)in_sizes; (void)n_in; (void)out_size;
    const float* x   = (const float*)d_in[0];
    const int*   roi = (const int*)d_in[1];
    const float* Wq  = (const float*)d_in[2];
    const float* Wk  = (const float*)d_in[3];
    const float* Wv  = (const float*)d_in[4];
    const float* Wc  = (const float*)d_in[5];
    const float* gam = (const float*)d_in[6];
    const float* bet = (const float*)d_in[7];
    float* out = (float*)d_out;

    const size_t EL = 33554432ull;                 // N*C*T*H*W
    const size_t need = EL * 2ull * 4ull + 2048ull;
    if (ws_size < need){
        sentinel_kernel<<<131072, 256, 0, stream>>>(out);
        return;
    }
    u16* qb    = (u16*)d_ws;
    u16* kb    = qb + EL;
    u16* vb    = kb + EL;
    u16* virtb = vb + EL;
    float* musig = (float*)(virtb + EL);

    // d_out scratch (134.2 MB): WtA [0, 4.7 MB); xpad [8 MB, 113 MB) during convs;
    // vt reuses [8 MB, 75 MB) after xpad is dead. virtn reuses kb+vb (ws, dead
    // after attn); WtC reuses qb (dead after attn).
    u16* WtA  = (u16*)d_out;
    u16* xpad = (u16*)d_out + (4u << 20);   // byte offset 8 MB
    u16* vt   = (u16*)d_out + (4u << 20);
    u16* virtn = kb;
    u16* WtC  = qb;

    xpad_kernel<<<dim3(256, 16), 256, 0, stream>>>(x, xpad);

    wt_kernel<<<9216, 256, 0, stream>>>(Wq, WtA);
    conv_mfma_kernel<<<1024, 256, 0, stream>>>(xpad, WtA, qb);
    wt_kernel<<<9216, 256, 0, stream>>>(Wk, WtA);
    conv_mfma_kernel<<<1024, 256, 0, stream>>>(xpad, WtA, kb);
    wt_kernel<<<9216, 256, 0, stream>>>(Wv, WtA);
    conv_mfma_kernel<<<1024, 256, 0, stream>>>(xpad, WtA, vb);

    vt_kernel<<<dim3(256, 32), 256, 0, stream>>>(vb, vt);
    attn_mfma_kernel<<<2048, 256, 0, stream>>>(qb, kb, vt, roi, virtb);
    stats_kernel<<<256, 256, 0, stream>>>(virtb, musig);

    virtn_kernel<<<dim3(256, 16), 256, 0, stream>>>(virtb, musig, gam, bet, virtn);
    wt_kernel<<<9216, 256, 0, stream>>>(Wc, WtC);
    conv_out_mfma_kernel<<<1024, 256, 0, stream>>>(virtn, WtC, x, out);
}